// Round 16
// baseline (369.248 us; speedup 1.0000x reference)
//
#include <hip/hip_runtime.h>
#include <hip/hip_bf16.h>
#include <hip/hip_fp16.h>
#include <math.h>

#define N_TOKENS 16
#define TOK_DIM 64
#define NODE_DIM 64
#define HID 128
#define FC 128
#define NUM_GRAPHS 1024
#define NBUCK_MAX 512
#define CHUNK 8192

typedef _Float16 f16x8 __attribute__((ext_vector_type(8)));
typedef float f32x4 __attribute__((ext_vector_type(4)));

__device__ __forceinline__ __half2 shfl_xor_h2(__half2 v, int mask) {
    int i = *(int*)&v;
    i = __shfl_xor(i, mask);
    return *(__half2*)&i;
}

// ---------------- phase A: weight prep + emb fp16 convert + per-chunk dst histogram ----------------
// grid = 128 (weights) + embBlocks (emb convert) + nchunk (hist), 256 threads
__global__ void phaseA_kernel(const float* __restrict__ Wp, const float* __restrict__ W1,
                              const float* __restrict__ W2, const float* __restrict__ bp,
                              _Float16* __restrict__ Wf16t, _Float16* __restrict__ W2t,
                              float* __restrict__ bf,
                              const float* __restrict__ emb, __half* __restrict__ emb16,
                              int emb_n4, int embBlocks,
                              const int* __restrict__ dst, int* __restrict__ cnt2D,
                              int E, int nbuck) {
    __shared__ int h[NBUCK_MAX];
    int bid = blockIdx.x;
    int t = threadIdx.x;
    if (bid < 128) {
        int n = bid;
        if (t < 64) {
            float acc = 0.f;
#pragma unroll
            for (int d = 0; d < 64; d++) acc += Wp[t * 64 + d] * W1[d * 128 + n];
            Wf16t[(size_t)n * 64 + t] = (_Float16)acc;
        } else if (t < 128) {
            int d = t - 64;  // lane of wave 1
            float v = bp[d] * W1[d * 128 + n];
#pragma unroll
            for (int off = 32; off > 0; off >>= 1) v += __shfl_down(v, off);
            if (d == 0) bf[n] = v;
        }
        if (t < 128) W2t[(size_t)n * 128 + t] = (_Float16)W2[(size_t)t * 128 + n];
    } else if (bid < 128 + embBlocks) {
        int i = (bid - 128) * 256 + t;
        if (i < emb_n4) {
            float4 v = ((const float4*)emb)[i];
            __half2 h0 = __floats2half2_rn(v.x, v.y);
            __half2 h1 = __floats2half2_rn(v.z, v.w);
            float2 p;
            ((__half2*)&p)[0] = h0;
            ((__half2*)&p)[1] = h1;
            ((float2*)emb16)[i] = p;
        }
    } else {
        int chunk = bid - 128 - embBlocks;
        for (int i = t; i < nbuck; i += 256) h[i] = 0;
        __syncthreads();
        int base = chunk * CHUNK;
        for (int i = t; i < CHUNK; i += 256) {
            int e = base + i;
            if (e < E) atomicAdd(&h[dst[e] >> 8], 1);
        }
        __syncthreads();
        for (int i = t; i < nbuck; i += 256) cnt2D[chunk * NBUCK_MAX + i] = h[i];
    }
}

// ---------------- bucket scan: totals from cnt2D -> bucket_base, zero cursors ----------------
// 1 block, 512 threads; nbuck <= 512
__global__ void bucket_scan_kernel(const int* __restrict__ cnt2D, int nchunk,
                                   int* __restrict__ bucket_base,
                                   int* __restrict__ bucket_cursor, int nbuck) {
    __shared__ int s[512];
    int tid = threadIdx.x;
    int total = 0;
    if (tid < nbuck)
        for (int c = 0; c < nchunk; c++) total += cnt2D[c * NBUCK_MAX + tid];
    s[tid] = total;
    __syncthreads();
    for (int off = 1; off < 512; off <<= 1) {
        int add = (tid >= off) ? s[tid - off] : 0;
        __syncthreads();
        s[tid] += add;
        __syncthreads();
    }
    if (tid < nbuck) { bucket_base[tid] = s[tid] - total; bucket_cursor[tid] = 0; }
    if (tid == 511) bucket_base[nbuck] = s[511];
}

// ---------------- binscatter: 2-pass LDS hist + cursor reservation, packed val = src | (dst&255)<<17 ----------------
__global__ void binscatter_kernel(const int* __restrict__ src, const int* __restrict__ dst,
                                  const int* __restrict__ bucket_base,
                                  int* __restrict__ bucket_cursor,
                                  int* __restrict__ staged, int E, int nbuck) {
    __shared__ int h[NBUCK_MAX];
    __shared__ int gw[NBUCK_MAX];
    int t = threadIdx.x;
    for (int i = t; i < nbuck; i += 512) h[i] = 0;
    __syncthreads();
    int base = blockIdx.x * CHUNK;
    for (int i = t; i < CHUNK; i += 512) {
        int e = base + i;
        if (e < E) atomicAdd(&h[dst[e] >> 8], 1);
    }
    __syncthreads();
    for (int i = t; i < nbuck; i += 512) {
        int c = h[i];
        gw[i] = (c > 0) ? bucket_base[i] + atomicAdd(&bucket_cursor[i], c) : 0;
        h[i] = 0;  // reuse as local rank cursor
    }
    __syncthreads();
    for (int i = t; i < CHUNK; i += 512) {
        int e = base + i;
        if (e < E) {
            int d = dst[e], s = src[e];
            int b = d >> 8;
            int r = atomicAdd(&h[b], 1);
            staged[gw[b] + r] = s | ((d & 255) << 17);
        }
    }
}

// ---------------- phase D: bucket_count (blocks < nbuck) + embed_mean (rest) ----------------
__global__ void countembed_kernel(const int* __restrict__ staged,
                                  const int* __restrict__ bucket_base,
                                  int* __restrict__ row_start, float* __restrict__ dis,
                                  const int* __restrict__ tok,
                                  const __half* __restrict__ emb16,
                                  __half* __restrict__ mean16,
                                  int N, int E, int nbuck) {
    __shared__ int cnt[256];
    __shared__ int sc[256];
    int bid = blockIdx.x;
    int t = threadIdx.x;
    if (bid < nbuck) {
        cnt[t] = 0;
        __syncthreads();
        int rb0 = bucket_base[bid], rb1 = bucket_base[bid + 1];
        for (int i = rb0 + t; i < rb1; i += 256) atomicAdd(&cnt[staged[i] >> 17], 1);
        __syncthreads();
        int v = cnt[t];
        sc[t] = v;
        __syncthreads();
        for (int off = 1; off < 256; off <<= 1) {
            int add = (t >= off) ? sc[t - off] : 0;
            __syncthreads();
            sc[t] += add;
            __syncthreads();
        }
        int node = bid * 256 + t;
        if (node < N) {
            row_start[node] = rb0 + sc[t] - v;    // exclusive
            dis[node] = rsqrtf(1.0f + (float)v);  // +1 self loop
        }
        if (bid == 0 && t == 0) row_start[N] = E;
    } else {
        // embed + token-mean (fp16 table, 8 rows/gather): lane (q,l), q=j>>3, l=j&7
        int w = t >> 6, j = t & 63;
        int q = j >> 3, l = j & 7;
        int i = (bid - nbuck) * 4 + w;
        if (i >= N) return;
        const float4* e4 = (const float4*)emb16;  // row = 8 float4 (64 halfs)
        int t0 = tok[i * 16 + q];
        int t1 = tok[i * 16 + q + 8];
        float4 v0 = e4[(size_t)t0 * 8 + l];
        float4 v1 = e4[(size_t)t1 * 8 + l];
        const __half2* p0 = (const __half2*)&v0;
        const __half2* p1 = (const __half2*)&v1;
        __half2 a0 = __hadd2(p0[0], p1[0]);
        __half2 a1 = __hadd2(p0[1], p1[1]);
        __half2 a2 = __hadd2(p0[2], p1[2]);
        __half2 a3 = __hadd2(p0[3], p1[3]);
#pragma unroll
        for (int mask = 8; mask <= 32; mask <<= 1) {
            a0 = __hadd2(a0, shfl_xor_h2(a0, mask));
            a1 = __hadd2(a1, shfl_xor_h2(a1, mask));
            a2 = __hadd2(a2, shfl_xor_h2(a2, mask));
            a3 = __hadd2(a3, shfl_xor_h2(a3, mask));
        }
        if (q == 0) {
            __half2 inv = __floats2half2_rn(1.0f / 16.0f, 1.0f / 16.0f);
            float4 packed;
            __half2* pp = (__half2*)&packed;
            pp[0] = __hmul2(a0, inv);
            pp[1] = __hmul2(a1, inv);
            pp[2] = __hmul2(a2, inv);
            pp[3] = __hmul2(a3, inv);
            ((float4*)mean16)[(size_t)i * 8 + l] = packed;
        }
    }
}

// ---------------- csr_write: final CSR (src, half2(w,w)) + rowsum ----------------
__global__ void csr_write_kernel(const int* __restrict__ staged,
                                 const int* __restrict__ bucket_base,
                                 const int* __restrict__ row_start,
                                 const float* __restrict__ dis,
                                 int2* __restrict__ csr, float* __restrict__ rowsum, int N) {
    __shared__ int cur[256];
    __shared__ float dl[256];
    __shared__ float wsum[256];
    int b = blockIdx.x;
    int t = threadIdx.x;
    int node = b * 256 + t;
    cur[t] = (node < N) ? row_start[node] : 0;
    dl[t] = (node < N) ? dis[node] : 0.f;
    wsum[t] = 0.f;
    __syncthreads();
    int rb0 = bucket_base[b], rb1 = bucket_base[b + 1];
    for (int i = rb0 + t; i < rb1; i += 256) {
        int v = staged[i];
        int s = v & 131071;
        int dloc = v >> 17;
        float w = dis[s] * dl[dloc];
        int pos = atomicAdd(&cur[dloc], 1);
        __half2 wh = __floats2half2_rn(w, w);
        csr[pos] = make_int2(s, *(int*)&wh);
        atomicAdd(&wsum[dloc], w);
    }
    __syncthreads();
    if (node < N) rowsum[node] = wsum[t] + dl[t] * dl[t];
}

// ---------------- agg64: fp16 packed accumulate, 8 rows per gather -> fp16 agg ----------------
__global__ __launch_bounds__(256, 8)
void agg64_kernel(const __half* __restrict__ mean16,
                  const int* __restrict__ row_start,
                  const int2* __restrict__ csr,
                  const float* __restrict__ dis,
                  __half* __restrict__ agg16, int N) {
    int t = threadIdx.x;
    int w = t >> 6, j = t & 63;
    int q = j >> 3, l = j & 7;
    int node = blockIdx.x * 4 + w;
    if (node >= N) return;
    int beg = row_start[node];
    int end = row_start[node + 1];
    float d = dis[node];
    const float4* m4 = (const float4*)mean16;  // row = 8 float4 (64 halfs)
    __half2 a0, a1, a2, a3;
    {
        float4 raw = m4[(size_t)node * 8 + l];
        const __half2* hp = (const __half2*)&raw;
        float d2f = d * d * ((q == 0) ? 1.f : 0.f);
        __half2 d2h = __floats2half2_rn(d2f, d2f);
        a0 = __hmul2(hp[0], d2h); a1 = __hmul2(hp[1], d2h);
        a2 = __hmul2(hp[2], d2h); a3 = __hmul2(hp[3], d2h);
    }
    int k = beg;
    int kfull = beg + ((end - beg) & ~31);
    for (; k < kfull; k += 32) {
        int2 e[4];
        float4 v[4];
#pragma unroll
        for (int m = 0; m < 4; m++) e[m] = csr[k + 8 * m + q];
#pragma unroll
        for (int m = 0; m < 4; m++) v[m] = m4[(size_t)e[m].x * 8 + l];
#pragma unroll
        for (int m = 0; m < 4; m++) {
            __half2 wh = *(__half2*)&e[m].y;
            const __half2* hp = (const __half2*)&v[m];
            a0 = __hfma2(hp[0], wh, a0);
            a1 = __hfma2(hp[1], wh, a1);
            a2 = __hfma2(hp[2], wh, a2);
            a3 = __hfma2(hp[3], wh, a3);
        }
    }
    for (; k < end; k += 16) {
        int2 e[2];
        float4 v[2];
#pragma unroll
        for (int m = 0; m < 2; m++) {
            int kk = k + 8 * m + q;
            e[m] = (kk < end) ? csr[kk] : make_int2(0, 0);
        }
#pragma unroll
        for (int m = 0; m < 2; m++) v[m] = m4[(size_t)e[m].x * 8 + l];
#pragma unroll
        for (int m = 0; m < 2; m++) {
            __half2 wh = *(__half2*)&e[m].y;
            const __half2* hp = (const __half2*)&v[m];
            a0 = __hfma2(hp[0], wh, a0);
            a1 = __hfma2(hp[1], wh, a1);
            a2 = __hfma2(hp[2], wh, a2);
            a3 = __hfma2(hp[3], wh, a3);
        }
    }
#pragma unroll
    for (int mask = 8; mask <= 32; mask <<= 1) {
        a0 = __hadd2(a0, shfl_xor_h2(a0, mask));
        a1 = __hadd2(a1, shfl_xor_h2(a1, mask));
        a2 = __hadd2(a2, shfl_xor_h2(a2, mask));
        a3 = __hadd2(a3, shfl_xor_h2(a3, mask));
    }
    if (q == 0) {
        float4 packed;
        __half2* pp = (__half2*)&packed;
        pp[0] = a0; pp[1] = a1; pp[2] = a2; pp[3] = a3;
        ((float4*)agg16)[(size_t)node * 8 + l] = packed;
    }
}

// ---------------- MFMA dense chain: h2 = relu(agg@Wf + rowsum*bf + b1) @ W2 -> fp16 ----------------
#define NB 32
__global__ void dense_chain_mfma_kernel(const __half* __restrict__ agg16,
                                        const float* __restrict__ rowsum,
                                        const _Float16* __restrict__ Wf16t,  // [128][64]
                                        const float* __restrict__ bf,
                                        const float* __restrict__ b1,
                                        const _Float16* __restrict__ W2t,    // [128][128]
                                        __half* __restrict__ h2, int N) {
    __shared__ _Float16 sx1[32][136];
    __shared__ float srs[32];
    int t = threadIdx.x;
    int wv = t >> 6, lane = t & 63;
    int nb0 = blockIdx.x * NB;
    int rh = wv & 1;
    int ncb = (wv >> 1) * 64;
    int m16 = lane & 15;
    int q = lane >> 4;

    if (t < 32) srs[t] = (nb0 + t < N) ? rowsum[nb0 + t] : 0.f;

    f32x4 c0 = {}, c1 = {}, c2 = {}, c3 = {};
    int arow = nb0 + rh * 16 + m16;
    bool rowok = (arow < N);
    const _Float16* ag = (const _Float16*)agg16;
#pragma unroll
    for (int ks = 0; ks < 2; ks++) {
        int k0 = ks * 32 + q * 8;
        f16x8 afrag = {};
        if (rowok) afrag = *(const f16x8*)(ag + (size_t)arow * 64 + k0);
        f16x8 b0 = *(const f16x8*)(Wf16t + (size_t)(ncb + 0 * 16 + m16) * 64 + k0);
        f16x8 b1f = *(const f16x8*)(Wf16t + (size_t)(ncb + 1 * 16 + m16) * 64 + k0);
        f16x8 b2f = *(const f16x8*)(Wf16t + (size_t)(ncb + 2 * 16 + m16) * 64 + k0);
        f16x8 b3f = *(const f16x8*)(Wf16t + (size_t)(ncb + 3 * 16 + m16) * 64 + k0);
        c0 = __builtin_amdgcn_mfma_f32_16x16x32_f16(afrag, b0, c0, 0, 0, 0);
        c1 = __builtin_amdgcn_mfma_f32_16x16x32_f16(afrag, b1f, c1, 0, 0, 0);
        c2 = __builtin_amdgcn_mfma_f32_16x16x32_f16(afrag, b2f, c2, 0, 0, 0);
        c3 = __builtin_amdgcn_mfma_f32_16x16x32_f16(afrag, b3f, c3, 0, 0, 0);
    }
    __syncthreads();
    {
        f32x4 cc[4] = {c0, c1, c2, c3};
#pragma unroll
        for (int nt = 0; nt < 4; nt++) {
            int ncol = ncb + nt * 16 + m16;
            float bfj = bf[ncol], b1j = b1[ncol];
#pragma unroll
            for (int r = 0; r < 4; r++) {
                int mrow = q * 4 + r;
                float z = cc[nt][r] + srs[rh * 16 + mrow] * bfj + b1j;
                sx1[rh * 16 + mrow][ncol] = (_Float16)fmaxf(z, 0.f);
            }
        }
    }
    __syncthreads();

    f32x4 d0 = {}, d1 = {}, d2 = {}, d3 = {};
#pragma unroll
    for (int ks = 0; ks < 4; ks++) {
        int k0 = ks * 32 + q * 8;
        f16x8 afrag = *(const f16x8*)(&sx1[rh * 16 + m16][k0]);
        f16x8 b0 = *(const f16x8*)(W2t + (size_t)(ncb + 0 * 16 + m16) * 128 + k0);
        f16x8 b1f = *(const f16x8*)(W2t + (size_t)(ncb + 1 * 16 + m16) * 128 + k0);
        f16x8 b2f = *(const f16x8*)(W2t + (size_t)(ncb + 2 * 16 + m16) * 128 + k0);
        f16x8 b3f = *(const f16x8*)(W2t + (size_t)(ncb + 3 * 16 + m16) * 128 + k0);
        d0 = __builtin_amdgcn_mfma_f32_16x16x32_f16(afrag, b0, d0, 0, 0, 0);
        d1 = __builtin_amdgcn_mfma_f32_16x16x32_f16(afrag, b1f, d1, 0, 0, 0);
        d2 = __builtin_amdgcn_mfma_f32_16x16x32_f16(afrag, b2f, d2, 0, 0, 0);
        d3 = __builtin_amdgcn_mfma_f32_16x16x32_f16(afrag, b3f, d3, 0, 0, 0);
    }
    {
        f32x4 dd[4] = {d0, d1, d2, d3};
#pragma unroll
        for (int nt = 0; nt < 4; nt++) {
            int ncol = ncb + nt * 16 + m16;
#pragma unroll
            for (int r = 0; r < 4; r++) {
                int node = nb0 + rh * 16 + q * 4 + r;
                if (node < N) h2[(size_t)node * 128 + ncol] = __float2half(dd[nt][r]);
            }
        }
    }
}

// ---------------- layer 2: agg128 fp16 packed accumulate, 4 rows per gather -> fp16 out ----------------
__global__ __launch_bounds__(256, 8)
void gcn_agg128_kernel(const __half* __restrict__ hsrc,
                       const int* __restrict__ row_start,
                       const int2* __restrict__ csr,
                       const float* __restrict__ dis,
                       const float* __restrict__ b2,
                       __half* __restrict__ outx, int N) {
    int t = threadIdx.x;
    int w = t >> 6, j = t & 63;
    int q = j >> 4, l = j & 15;
    int node = blockIdx.x * 4 + w;
    if (node >= N) return;
    const float4* h4 = (const float4*)hsrc;  // row = 16 float4 (128 halfs)
    int beg = row_start[node];
    int end = row_start[node + 1];
    float d = dis[node];
    __half2 a0, a1, a2, a3;
    {
        float4 raw = h4[(size_t)node * 16 + l];
        const __half2* hp = (const __half2*)&raw;
        float d2f = d * d * ((q == 0) ? 1.f : 0.f);
        __half2 d2h = __floats2half2_rn(d2f, d2f);
        a0 = __hmul2(hp[0], d2h); a1 = __hmul2(hp[1], d2h);
        a2 = __hmul2(hp[2], d2h); a3 = __hmul2(hp[3], d2h);
    }
    int k = beg;
    int kfull = beg + ((end - beg) & ~31);
    for (; k < kfull; k += 32) {
        int2 e[8];
        float4 v[8];
#pragma unroll
        for (int m = 0; m < 8; m++) e[m] = csr[k + 4 * m + q];
#pragma unroll
        for (int m = 0; m < 8; m++) v[m] = h4[(size_t)e[m].x * 16 + l];
#pragma unroll
        for (int m = 0; m < 8; m++) {
            __half2 wh = *(__half2*)&e[m].y;
            const __half2* hp = (const __half2*)&v[m];
            a0 = __hfma2(hp[0], wh, a0);
            a1 = __hfma2(hp[1], wh, a1);
            a2 = __hfma2(hp[2], wh, a2);
            a3 = __hfma2(hp[3], wh, a3);
        }
    }
    for (; k < end; k += 16) {
        int2 e[4];
        float4 v[4];
#pragma unroll
        for (int m = 0; m < 4; m++) {
            int kk = k + 4 * m + q;
            e[m] = (kk < end) ? csr[kk] : make_int2(0, 0);
        }
#pragma unroll
        for (int m = 0; m < 4; m++) v[m] = h4[(size_t)e[m].x * 16 + l];
#pragma unroll
        for (int m = 0; m < 4; m++) {
            __half2 wh = *(__half2*)&e[m].y;
            const __half2* hp = (const __half2*)&v[m];
            a0 = __hfma2(hp[0], wh, a0);
            a1 = __hfma2(hp[1], wh, a1);
            a2 = __hfma2(hp[2], wh, a2);
            a3 = __hfma2(hp[3], wh, a3);
        }
    }
#pragma unroll
    for (int mask = 16; mask <= 32; mask <<= 1) {
        a0 = __hadd2(a0, shfl_xor_h2(a0, mask));
        a1 = __hadd2(a1, shfl_xor_h2(a1, mask));
        a2 = __hadd2(a2, shfl_xor_h2(a2, mask));
        a3 = __hadd2(a3, shfl_xor_h2(a3, mask));
    }
    if (q == 0) {
        float2 f0 = __half22float2(a0), f1 = __half22float2(a1);
        float2 f2 = __half22float2(a2), f3 = __half22float2(a3);
        const float4* b4 = (const float4*)b2;
        float4 ba = b4[l * 2], bb = b4[l * 2 + 1];
        __half2 o0 = __floats2half2_rn(fmaxf(f0.x + ba.x, 0.f), fmaxf(f0.y + ba.y, 0.f));
        __half2 o1 = __floats2half2_rn(fmaxf(f1.x + ba.z, 0.f), fmaxf(f1.y + ba.w, 0.f));
        __half2 o2 = __floats2half2_rn(fmaxf(f2.x + bb.x, 0.f), fmaxf(f2.y + bb.y, 0.f));
        __half2 o3 = __floats2half2_rn(fmaxf(f3.x + bb.z, 0.f), fmaxf(f3.y + bb.w, 0.f));
        float4 packed;
        __half2* pp = (__half2*)&packed;
        pp[0] = o0; pp[1] = o1; pp[2] = o2; pp[3] = o3;
        ((float4*)outx)[(size_t)node * 16 + l] = packed;
    }
}

// ---------------- fused pool + head: one block (128 threads) per graph ----------------
__device__ __forceinline__ int lower_bound_i(const int* __restrict__ a, int n, int val) {
    int lo = 0, hi = n;
    while (lo < hi) {
        int mid = (lo + hi) >> 1;
        if (a[mid] < val) lo = mid + 1; else hi = mid;
    }
    return lo;
}

__global__ void pool_head_kernel(const __half* __restrict__ x,
                                 const int* __restrict__ batch,
                                 const float* __restrict__ Wfc,
                                 const float* __restrict__ bfc,
                                 const float* __restrict__ Wout,
                                 const float* __restrict__ bout,
                                 float* __restrict__ out, int N) {
    int gr = blockIdx.x;
    int t = threadIdx.x;  // 0..127
    int j2 = t & 63, w = t >> 6;
    __shared__ float2 spart[2][64];
    __shared__ float sg[128];
    __shared__ float sred[128];
    int beg = lower_bound_i(batch, N, gr);
    int end = lower_bound_i(batch, N, gr + 1);
    const __half2* x2 = (const __half2*)x;  // row stride 64 half2
    float2 acc = make_float2(0.f, 0.f);
    for (int i = beg + w; i < end; i += 2) {
        float2 a = __half22float2(x2[(size_t)i * 64 + j2]);
        acc.x += a.x; acc.y += a.y;
    }
    spart[w][j2] = acc;
    __syncthreads();
    if (t < 64) {
        float inv = 1.0f / fmaxf((float)(end - beg), 1.0f);
        float2 s0 = spart[0][t], s1 = spart[1][t];
        sg[2 * t] = (s0.x + s1.x) * inv;
        sg[2 * t + 1] = (s0.y + s1.y) * inv;
    }
    __syncthreads();
    int j = t;
    float a = bfc[j];
#pragma unroll
    for (int k = 0; k < 128; k++) a += sg[k] * Wfc[k * 128 + j];
    float f = fmaxf(a, 0.f);
    sred[j] = f * Wout[j];
    __syncthreads();
    if (j < 64) sred[j] += sred[j + 64];
    __syncthreads();
    if (j < 64) {
        float v = sred[j];
#pragma unroll
        for (int off = 32; off > 0; off >>= 1) v += __shfl_down(v, off);
        if (j == 0) {
            float logit = v + bout[0];
            out[gr] = 1.0f / (1.0f + expf(-logit));
            out[NUM_GRAPHS + gr] = logit;
        }
    }
}

extern "C" void kernel_launch(void* const* d_in, const int* in_sizes, int n_in,
                              void* d_out, int out_size, void* d_ws, size_t ws_size,
                              hipStream_t stream) {
    const int* tok   = (const int*)d_in[0];
    const int* eidx  = (const int*)d_in[1];
    const int* batch = (const int*)d_in[2];
    const float* emb = (const float*)d_in[3];
    const float* Wp  = (const float*)d_in[4];
    const float* bp  = (const float*)d_in[5];
    const float* W1  = (const float*)d_in[6];
    const float* b1  = (const float*)d_in[7];
    const float* W2  = (const float*)d_in[8];
    const float* b2  = (const float*)d_in[9];
    const float* Wfc = (const float*)d_in[10];
    const float* bfc = (const float*)d_in[11];
    const float* Wout= (const float*)d_in[12];
    const float* bout= (const float*)d_in[13];
    float* out = (float*)d_out;

    const int N = in_sizes[2];
    const int E = in_sizes[1] / 2;
    const int* src = eidx;
    const int* dst = eidx + E;
    const int Np = (N + 3) & ~3;
    const int nbuck = (N + 255) / 256;               // 391 for N=100k
    const int nchunk = (E + CHUNK - 1) / CHUNK;      // 196
    const int emb_n4 = in_sizes[3] / 4;              // float4 count of emb
    const int embBlocks = (emb_n4 + 255) / 256;      // 2000

    // workspace layout (float units)
    float* ws = (float*)d_ws;
    size_t off = 0;
    float* dis     = ws + off;            off += Np;
    __half* mean16 = (__half*)(ws + off); off += (size_t)Np * 32;
    __half* agg16  = (__half*)(ws + off); off += (size_t)Np * 32;
    float* rowsum  = ws + off;            off += Np;
    __half* h2buf  = (__half*)(ws + off); off += (size_t)Np * 64;
    __half* xfin16 = (__half*)(ws + off); off += (size_t)Np * 64;
    __half* emb16  = (__half*)(ws + off); off += (size_t)(in_sizes[3] / 2 + 4);
    _Float16* Wf16t = (_Float16*)(ws + off); off += 4096;
    _Float16* W2t   = (_Float16*)(ws + off); off += 8192;
    float* bf      = ws + off;            off += 128;
    int* row_start = (int*)(ws + off);    off += Np + 4;
    int* staged    = (int*)(ws + off);    off += E;
    int* cnt2D     = (int*)(ws + off);    off += (size_t)nchunk * NBUCK_MAX;
    int* bucket_base   = (int*)(ws + off); off += NBUCK_MAX + 8;
    int* bucket_cursor = (int*)(ws + off); off += NBUCK_MAX;
    int2* csr      = (int2*)(ws + off);   // E int2

    // --- A: weight prep + emb fp16 convert + per-chunk hist (one launch) ---
    phaseA_kernel<<<128 + embBlocks + nchunk, 256, 0, stream>>>(
        Wp, W1, W2, bp, Wf16t, W2t, bf, emb, emb16, emb_n4, embBlocks,
        dst, cnt2D, E, nbuck);

    // --- B: bucket scan (totals from cnt2D; zeroes cursors) ---
    bucket_scan_kernel<<<1, 512, 0, stream>>>(cnt2D, nchunk, bucket_base, bucket_cursor,
                                              nbuck);

    // --- C: binscatter ---
    binscatter_kernel<<<nchunk, 512, 0, stream>>>(src, dst, bucket_base, bucket_cursor,
                                                  staged, E, nbuck);

    // --- D: bucket count (row_start, dis) + embed token-mean (one launch) ---
    countembed_kernel<<<nbuck + (N + 3) / 4, 256, 0, stream>>>(
        staged, bucket_base, row_start, dis, tok, emb16, mean16, N, E, nbuck);

    // --- E: csr write (+rowsum) ---
    csr_write_kernel<<<nbuck, 256, 0, stream>>>(staged, bucket_base, row_start, dis,
                                                csr, rowsum, N);

    // --- F: 64-dim aggregate (fp16 packed) -> agg16 ---
    agg64_kernel<<<(N + 3) / 4, 256, 0, stream>>>(mean16, row_start, csr, dis, agg16, N);

    // --- G: MFMA dense chain: h2 = relu(agg@Wf + rowsum*bf + b1) @ W2 -> fp16 ---
    dense_chain_mfma_kernel<<<(N + NB - 1) / NB, 256, 0, stream>>>(agg16, rowsum, Wf16t,
                                                                   bf, b1, W2t, h2buf, N);

    // --- H: layer 2 aggregate (fp16 packed) + b2 + ReLU -> xfin16 ---
    gcn_agg128_kernel<<<(N + 3) / 4, 256, 0, stream>>>(h2buf, row_start, csr, dis, b2,
                                                       xfin16, N);

    // --- I: fused global mean pool + head ---
    pool_head_kernel<<<NUM_GRAPHS, 128, 0, stream>>>(xfin16, batch, Wfc, bfc, Wout, bout,
                                                     out, N);
}

// Round 17
// 348.827 us; speedup vs baseline: 1.0585x; 1.0585x over previous
//
#include <hip/hip_runtime.h>
#include <hip/hip_bf16.h>
#include <hip/hip_fp16.h>
#include <math.h>

#define N_TOKENS 16
#define TOK_DIM 64
#define NODE_DIM 64
#define HID 128
#define FC 128
#define NUM_GRAPHS 1024
#define NBUCK_MAX 512
#define CHUNK 8192

typedef _Float16 f16x8 __attribute__((ext_vector_type(8)));
typedef float f32x4 __attribute__((ext_vector_type(4)));

__device__ __forceinline__ __half2 shfl_xor_h2(__half2 v, int mask) {
    int i = *(int*)&v;
    i = __shfl_xor(i, mask);
    return *(__half2*)&i;
}

// ---------------- fused weight prep: Wf16t = (Wp@W1)^T fp16, W2t = W2^T fp16, bf = bp@W1 ----------------
__global__ void prep_weights_kernel(const float* __restrict__ Wp, const float* __restrict__ W1,
                                    const float* __restrict__ W2, const float* __restrict__ bp,
                                    _Float16* __restrict__ Wf16t, _Float16* __restrict__ W2t,
                                    float* __restrict__ bf) {
    int n = blockIdx.x;   // 0..127
    int t = threadIdx.x;  // 0..127
    if (t < 64) {
        float acc = 0.f;
#pragma unroll
        for (int d = 0; d < 64; d++) acc += Wp[t * 64 + d] * W1[d * 128 + n];
        Wf16t[(size_t)n * 64 + t] = (_Float16)acc;
    } else {
        int d = t - 64;  // lane of wave 1
        float v = bp[d] * W1[d * 128 + n];
#pragma unroll
        for (int off = 32; off > 0; off >>= 1) v += __shfl_down(v, off);
        if (d == 0) bf[n] = v;
    }
    W2t[(size_t)n * 128 + t] = (_Float16)W2[(size_t)t * 128 + n];
}

// ---------------- emb fp32 -> fp16 table ----------------
__global__ void convert_emb_kernel(const float* __restrict__ emb, __half* __restrict__ emb16,
                                   int n4) {
    int i = blockIdx.x * 256 + threadIdx.x;
    if (i < n4) {
        float4 v = ((const float4*)emb)[i];
        __half2 h0 = __floats2half2_rn(v.x, v.y);
        __half2 h1 = __floats2half2_rn(v.z, v.w);
        float2 p;
        ((__half2*)&p)[0] = h0;
        ((__half2*)&p)[1] = h1;
        ((float2*)emb16)[i] = p;
    }
}

// ---------------- embed + token-mean (fp16 table, 8 rows/gather) -> mean16[N,64] ----------------
// lane (q,l): q=j>>3 token slot (8), l=j&7 feature block (float4 = 8 halfs)
__global__ void embed_mean_kernel(const int* __restrict__ tok,
                                  const __half* __restrict__ emb16,
                                  __half* __restrict__ mean16, int N) {
    int t = threadIdx.x;
    int w = t >> 6, j = t & 63;
    int q = j >> 3, l = j & 7;
    int i = blockIdx.x * 4 + w;
    if (i >= N) return;
    const float4* e4 = (const float4*)emb16;  // row = 8 float4 (64 halfs)
    int t0 = tok[i * 16 + q];
    int t1 = tok[i * 16 + q + 8];
    float4 v0 = e4[(size_t)t0 * 8 + l];
    float4 v1 = e4[(size_t)t1 * 8 + l];
    const __half2* p0 = (const __half2*)&v0;
    const __half2* p1 = (const __half2*)&v1;
    __half2 a0 = __hadd2(p0[0], p1[0]);
    __half2 a1 = __hadd2(p0[1], p1[1]);
    __half2 a2 = __hadd2(p0[2], p1[2]);
    __half2 a3 = __hadd2(p0[3], p1[3]);
#pragma unroll
    for (int mask = 8; mask <= 32; mask <<= 1) {
        a0 = __hadd2(a0, shfl_xor_h2(a0, mask));
        a1 = __hadd2(a1, shfl_xor_h2(a1, mask));
        a2 = __hadd2(a2, shfl_xor_h2(a2, mask));
        a3 = __hadd2(a3, shfl_xor_h2(a3, mask));
    }
    if (q == 0) {
        __half2 inv = __floats2half2_rn(1.0f / 16.0f, 1.0f / 16.0f);
        float4 packed;
        __half2* pp = (__half2*)&packed;
        pp[0] = __hmul2(a0, inv);
        pp[1] = __hmul2(a1, inv);
        pp[2] = __hmul2(a2, inv);
        pp[3] = __hmul2(a3, inv);
        ((float4*)mean16)[(size_t)i * 8 + l] = packed;
    }
}

// ---------------- bucketed counting sort: dst buckets of 256 nodes (512-thread blocks) ----------------
__global__ void bucket_hist_kernel(const int* __restrict__ dst, int* __restrict__ bucket_cnt,
                                   int E, int nbuck) {
    __shared__ int h[NBUCK_MAX];
    int t = threadIdx.x;
    for (int i = t; i < nbuck; i += 512) h[i] = 0;
    __syncthreads();
    int base = blockIdx.x * CHUNK;
    for (int i = t; i < CHUNK; i += 512) {
        int e = base + i;
        if (e < E) atomicAdd(&h[dst[e] >> 8], 1);
    }
    __syncthreads();
    for (int i = t; i < nbuck; i += 512)
        if (h[i]) atomicAdd(&bucket_cnt[i], h[i]);
}

// 1 block, 512 threads; nbuck <= 512
__global__ void bucket_scan_kernel(const int* __restrict__ bucket_cnt,
                                   int* __restrict__ bucket_base,
                                   int* __restrict__ bucket_cursor, int nbuck) {
    __shared__ int s[512];
    int tid = threadIdx.x;
    int v = (tid < nbuck) ? bucket_cnt[tid] : 0;
    s[tid] = v;
    __syncthreads();
    for (int off = 1; off < 512; off <<= 1) {
        int add = (tid >= off) ? s[tid - off] : 0;
        __syncthreads();
        s[tid] += add;
        __syncthreads();
    }
    if (tid < nbuck) { bucket_base[tid] = s[tid] - v; bucket_cursor[tid] = 0; }
    if (tid == 511) bucket_base[nbuck] = s[511];
}

// scatter edges into bucket-contiguous staging, packed val = src | (dst&255)<<17
__global__ void binscatter_kernel(const int* __restrict__ src, const int* __restrict__ dst,
                                  const int* __restrict__ bucket_base,
                                  int* __restrict__ bucket_cursor,
                                  int* __restrict__ staged, int E, int nbuck) {
    __shared__ int h[NBUCK_MAX];
    __shared__ int gw[NBUCK_MAX];
    int t = threadIdx.x;
    for (int i = t; i < nbuck; i += 512) h[i] = 0;
    __syncthreads();
    int base = blockIdx.x * CHUNK;
    for (int i = t; i < CHUNK; i += 512) {
        int e = base + i;
        if (e < E) atomicAdd(&h[dst[e] >> 8], 1);
    }
    __syncthreads();
    for (int i = t; i < nbuck; i += 512) {
        int c = h[i];
        gw[i] = (c > 0) ? bucket_base[i] + atomicAdd(&bucket_cursor[i], c) : 0;
        h[i] = 0;  // reuse as local rank cursor
    }
    __syncthreads();
    for (int i = t; i < CHUNK; i += 512) {
        int e = base + i;
        if (e < E) {
            int d = dst[e], s = src[e];
            int b = d >> 8;
            int r = atomicAdd(&h[b], 1);
            staged[gw[b] + r] = s | ((d & 255) << 17);
        }
    }
}

// per bucket: per-node degree -> row_start + dis (coalesced writes)
__global__ void bucket_count_kernel(const int* __restrict__ staged,
                                    const int* __restrict__ bucket_base,
                                    int* __restrict__ row_start, float* __restrict__ dis,
                                    int N, int E) {
    __shared__ int cnt[256];
    __shared__ int sc[256];
    int b = blockIdx.x;
    int t = threadIdx.x;
    cnt[t] = 0;
    __syncthreads();
    int rb0 = bucket_base[b], rb1 = bucket_base[b + 1];
    for (int i = rb0 + t; i < rb1; i += 256) atomicAdd(&cnt[staged[i] >> 17], 1);
    __syncthreads();
    int v = cnt[t];
    sc[t] = v;
    __syncthreads();
    for (int off = 1; off < 256; off <<= 1) {
        int add = (t >= off) ? sc[t - off] : 0;
        __syncthreads();
        sc[t] += add;
        __syncthreads();
    }
    int node = b * 256 + t;
    if (node < N) {
        row_start[node] = rb0 + sc[t] - v;  // exclusive
        dis[node] = rsqrtf(1.0f + (float)v);  // +1 self loop
    }
    if (b == 0 && t == 0) row_start[N] = E;
}

// per bucket: final CSR (src, half2(w,w)) + rowsum — block-local contiguous region
__global__ void csr_write_kernel(const int* __restrict__ staged,
                                 const int* __restrict__ bucket_base,
                                 const int* __restrict__ row_start,
                                 const float* __restrict__ dis,
                                 int2* __restrict__ csr, float* __restrict__ rowsum, int N) {
    __shared__ int cur[256];
    __shared__ float dl[256];
    __shared__ float wsum[256];
    int b = blockIdx.x;
    int t = threadIdx.x;
    int node = b * 256 + t;
    cur[t] = (node < N) ? row_start[node] : 0;
    dl[t] = (node < N) ? dis[node] : 0.f;
    wsum[t] = 0.f;
    __syncthreads();
    int rb0 = bucket_base[b], rb1 = bucket_base[b + 1];
    for (int i = rb0 + t; i < rb1; i += 256) {
        int v = staged[i];
        int s = v & 131071;
        int dloc = v >> 17;
        float w = dis[s] * dl[dloc];
        int pos = atomicAdd(&cur[dloc], 1);
        __half2 wh = __floats2half2_rn(w, w);
        csr[pos] = make_int2(s, *(int*)&wh);
        atomicAdd(&wsum[dloc], w);
    }
    __syncthreads();
    if (node < N) rowsum[node] = wsum[t] + dl[t] * dl[t];
}

// ---------------- agg64: fp16 packed accumulate, 8 rows per gather -> fp16 agg ----------------
// lane (q,l): q=j>>3 edge slot (8), l=j&7 feature block (float4 = 4 half2)
__global__ __launch_bounds__(256, 8)
void agg64_kernel(const __half* __restrict__ mean16,
                  const int* __restrict__ row_start,
                  const int2* __restrict__ csr,
                  const float* __restrict__ dis,
                  __half* __restrict__ agg16, int N) {
    int t = threadIdx.x;
    int w = t >> 6, j = t & 63;
    int q = j >> 3, l = j & 7;
    int node = blockIdx.x * 4 + w;
    if (node >= N) return;
    int beg = row_start[node];
    int end = row_start[node + 1];
    float d = dis[node];
    const float4* m4 = (const float4*)mean16;  // row = 8 float4 (64 halfs)
    __half2 a0, a1, a2, a3;
    {
        float4 raw = m4[(size_t)node * 8 + l];
        const __half2* hp = (const __half2*)&raw;
        float d2f = d * d * ((q == 0) ? 1.f : 0.f);
        __half2 d2h = __floats2half2_rn(d2f, d2f);
        a0 = __hmul2(hp[0], d2h); a1 = __hmul2(hp[1], d2h);
        a2 = __hmul2(hp[2], d2h); a3 = __hmul2(hp[3], d2h);
    }
    int k = beg;
    int kfull = beg + ((end - beg) & ~31);
    for (; k < kfull; k += 32) {  // unguarded: 4 batches x 8 slots
        int2 e[4];
        float4 v[4];
#pragma unroll
        for (int m = 0; m < 4; m++) e[m] = csr[k + 8 * m + q];
#pragma unroll
        for (int m = 0; m < 4; m++) v[m] = m4[(size_t)e[m].x * 8 + l];
#pragma unroll
        for (int m = 0; m < 4; m++) {
            __half2 wh = *(__half2*)&e[m].y;
            const __half2* hp = (const __half2*)&v[m];
            a0 = __hfma2(hp[0], wh, a0);
            a1 = __hfma2(hp[1], wh, a1);
            a2 = __hfma2(hp[2], wh, a2);
            a3 = __hfma2(hp[3], wh, a3);
        }
    }
    for (; k < end; k += 16) {  // guarded tail: 2 batches x 8 slots
        int2 e[2];
        float4 v[2];
#pragma unroll
        for (int m = 0; m < 2; m++) {
            int kk = k + 8 * m + q;
            e[m] = (kk < end) ? csr[kk] : make_int2(0, 0);  // wh=0 => no-op
        }
#pragma unroll
        for (int m = 0; m < 2; m++) v[m] = m4[(size_t)e[m].x * 8 + l];
#pragma unroll
        for (int m = 0; m < 2; m++) {
            __half2 wh = *(__half2*)&e[m].y;
            const __half2* hp = (const __half2*)&v[m];
            a0 = __hfma2(hp[0], wh, a0);
            a1 = __hfma2(hp[1], wh, a1);
            a2 = __hfma2(hp[2], wh, a2);
            a3 = __hfma2(hp[3], wh, a3);
        }
    }
    // fold across q (lane bits 3,4,5)
#pragma unroll
    for (int mask = 8; mask <= 32; mask <<= 1) {
        a0 = __hadd2(a0, shfl_xor_h2(a0, mask));
        a1 = __hadd2(a1, shfl_xor_h2(a1, mask));
        a2 = __hadd2(a2, shfl_xor_h2(a2, mask));
        a3 = __hadd2(a3, shfl_xor_h2(a3, mask));
    }
    if (q == 0) {
        float4 packed;
        __half2* pp = (__half2*)&packed;
        pp[0] = a0; pp[1] = a1; pp[2] = a2; pp[3] = a3;
        ((float4*)agg16)[(size_t)node * 8 + l] = packed;
    }
}

// ---------------- MFMA dense chain: h2 = relu(agg@Wf + rowsum*bf + b1) @ W2 -> fp16 ----------------
#define NB 32
__global__ void dense_chain_mfma_kernel(const __half* __restrict__ agg16,
                                        const float* __restrict__ rowsum,
                                        const _Float16* __restrict__ Wf16t,  // [128][64]
                                        const float* __restrict__ bf,
                                        const float* __restrict__ b1,
                                        const _Float16* __restrict__ W2t,    // [128][128]
                                        __half* __restrict__ h2, int N) {
    __shared__ _Float16 sx1[32][136];
    __shared__ float srs[32];
    int t = threadIdx.x;
    int wv = t >> 6, lane = t & 63;
    int nb0 = blockIdx.x * NB;
    int rh = wv & 1;
    int ncb = (wv >> 1) * 64;
    int m16 = lane & 15;
    int q = lane >> 4;

    if (t < 32) srs[t] = (nb0 + t < N) ? rowsum[nb0 + t] : 0.f;

    f32x4 c0 = {}, c1 = {}, c2 = {}, c3 = {};
    int arow = nb0 + rh * 16 + m16;
    bool rowok = (arow < N);
    const _Float16* ag = (const _Float16*)agg16;
#pragma unroll
    for (int ks = 0; ks < 2; ks++) {
        int k0 = ks * 32 + q * 8;
        f16x8 afrag = {};
        if (rowok) afrag = *(const f16x8*)(ag + (size_t)arow * 64 + k0);
        f16x8 b0 = *(const f16x8*)(Wf16t + (size_t)(ncb + 0 * 16 + m16) * 64 + k0);
        f16x8 b1f = *(const f16x8*)(Wf16t + (size_t)(ncb + 1 * 16 + m16) * 64 + k0);
        f16x8 b2f = *(const f16x8*)(Wf16t + (size_t)(ncb + 2 * 16 + m16) * 64 + k0);
        f16x8 b3f = *(const f16x8*)(Wf16t + (size_t)(ncb + 3 * 16 + m16) * 64 + k0);
        c0 = __builtin_amdgcn_mfma_f32_16x16x32_f16(afrag, b0, c0, 0, 0, 0);
        c1 = __builtin_amdgcn_mfma_f32_16x16x32_f16(afrag, b1f, c1, 0, 0, 0);
        c2 = __builtin_amdgcn_mfma_f32_16x16x32_f16(afrag, b2f, c2, 0, 0, 0);
        c3 = __builtin_amdgcn_mfma_f32_16x16x32_f16(afrag, b3f, c3, 0, 0, 0);
    }
    __syncthreads();
    {
        f32x4 cc[4] = {c0, c1, c2, c3};
#pragma unroll
        for (int nt = 0; nt < 4; nt++) {
            int ncol = ncb + nt * 16 + m16;
            float bfj = bf[ncol], b1j = b1[ncol];
#pragma unroll
            for (int r = 0; r < 4; r++) {
                int mrow = q * 4 + r;
                float z = cc[nt][r] + srs[rh * 16 + mrow] * bfj + b1j;
                sx1[rh * 16 + mrow][ncol] = (_Float16)fmaxf(z, 0.f);
            }
        }
    }
    __syncthreads();

    f32x4 d0 = {}, d1 = {}, d2 = {}, d3 = {};
#pragma unroll
    for (int ks = 0; ks < 4; ks++) {
        int k0 = ks * 32 + q * 8;
        f16x8 afrag = *(const f16x8*)(&sx1[rh * 16 + m16][k0]);
        f16x8 b0 = *(const f16x8*)(W2t + (size_t)(ncb + 0 * 16 + m16) * 128 + k0);
        f16x8 b1f = *(const f16x8*)(W2t + (size_t)(ncb + 1 * 16 + m16) * 128 + k0);
        f16x8 b2f = *(const f16x8*)(W2t + (size_t)(ncb + 2 * 16 + m16) * 128 + k0);
        f16x8 b3f = *(const f16x8*)(W2t + (size_t)(ncb + 3 * 16 + m16) * 128 + k0);
        d0 = __builtin_amdgcn_mfma_f32_16x16x32_f16(afrag, b0, d0, 0, 0, 0);
        d1 = __builtin_amdgcn_mfma_f32_16x16x32_f16(afrag, b1f, d1, 0, 0, 0);
        d2 = __builtin_amdgcn_mfma_f32_16x16x32_f16(afrag, b2f, d2, 0, 0, 0);
        d3 = __builtin_amdgcn_mfma_f32_16x16x32_f16(afrag, b3f, d3, 0, 0, 0);
    }
    {
        f32x4 dd[4] = {d0, d1, d2, d3};
#pragma unroll
        for (int nt = 0; nt < 4; nt++) {
            int ncol = ncb + nt * 16 + m16;
#pragma unroll
            for (int r = 0; r < 4; r++) {
                int node = nb0 + rh * 16 + q * 4 + r;
                if (node < N) h2[(size_t)node * 128 + ncol] = __float2half(dd[nt][r]);
            }
        }
    }
}

// ---------------- layer 2: agg128 fp16 packed accumulate, 4 rows per gather -> fp16 out ----------------
// lane (q,l): q=j>>4 edge slot (4), l=j&15 feature block (float4 = 4 half2)
__global__ __launch_bounds__(256, 8)
void gcn_agg128_kernel(const __half* __restrict__ hsrc,
                       const int* __restrict__ row_start,
                       const int2* __restrict__ csr,
                       const float* __restrict__ dis,
                       const float* __restrict__ b2,
                       __half* __restrict__ outx, int N) {
    int t = threadIdx.x;
    int w = t >> 6, j = t & 63;
    int q = j >> 4, l = j & 15;
    int node = blockIdx.x * 4 + w;
    if (node >= N) return;
    const float4* h4 = (const float4*)hsrc;  // row = 16 float4 (128 halfs)
    int beg = row_start[node];
    int end = row_start[node + 1];
    float d = dis[node];
    __half2 a0, a1, a2, a3;
    {
        float4 raw = h4[(size_t)node * 16 + l];
        const __half2* hp = (const __half2*)&raw;
        float d2f = d * d * ((q == 0) ? 1.f : 0.f);
        __half2 d2h = __floats2half2_rn(d2f, d2f);
        a0 = __hmul2(hp[0], d2h); a1 = __hmul2(hp[1], d2h);
        a2 = __hmul2(hp[2], d2h); a3 = __hmul2(hp[3], d2h);
    }
    int k = beg;
    int kfull = beg + ((end - beg) & ~31);
    for (; k < kfull; k += 32) {  // unguarded: 8 batches x 4 slots
        int2 e[8];
        float4 v[8];
#pragma unroll
        for (int m = 0; m < 8; m++) e[m] = csr[k + 4 * m + q];
#pragma unroll
        for (int m = 0; m < 8; m++) v[m] = h4[(size_t)e[m].x * 16 + l];
#pragma unroll
        for (int m = 0; m < 8; m++) {
            __half2 wh = *(__half2*)&e[m].y;
            const __half2* hp = (const __half2*)&v[m];
            a0 = __hfma2(hp[0], wh, a0);
            a1 = __hfma2(hp[1], wh, a1);
            a2 = __hfma2(hp[2], wh, a2);
            a3 = __hfma2(hp[3], wh, a3);
        }
    }
    for (; k < end; k += 16) {  // guarded tail: 4 batches x 4 slots
        int2 e[4];
        float4 v[4];
#pragma unroll
        for (int m = 0; m < 4; m++) {
            int kk = k + 4 * m + q;
            e[m] = (kk < end) ? csr[kk] : make_int2(0, 0);
        }
#pragma unroll
        for (int m = 0; m < 4; m++) v[m] = h4[(size_t)e[m].x * 16 + l];
#pragma unroll
        for (int m = 0; m < 4; m++) {
            __half2 wh = *(__half2*)&e[m].y;
            const __half2* hp = (const __half2*)&v[m];
            a0 = __hfma2(hp[0], wh, a0);
            a1 = __hfma2(hp[1], wh, a1);
            a2 = __hfma2(hp[2], wh, a2);
            a3 = __hfma2(hp[3], wh, a3);
        }
    }
    // fold across q (lane bits 4,5)
#pragma unroll
    for (int mask = 16; mask <= 32; mask <<= 1) {
        a0 = __hadd2(a0, shfl_xor_h2(a0, mask));
        a1 = __hadd2(a1, shfl_xor_h2(a1, mask));
        a2 = __hadd2(a2, shfl_xor_h2(a2, mask));
        a3 = __hadd2(a3, shfl_xor_h2(a3, mask));
    }
    if (q == 0) {
        // fp32 epilogue: + b2, relu, pack fp16
        float2 f0 = __half22float2(a0), f1 = __half22float2(a1);
        float2 f2 = __half22float2(a2), f3 = __half22float2(a3);
        const float4* b4 = (const float4*)b2;
        float4 ba = b4[l * 2], bb = b4[l * 2 + 1];
        __half2 o0 = __floats2half2_rn(fmaxf(f0.x + ba.x, 0.f), fmaxf(f0.y + ba.y, 0.f));
        __half2 o1 = __floats2half2_rn(fmaxf(f1.x + ba.z, 0.f), fmaxf(f1.y + ba.w, 0.f));
        __half2 o2 = __floats2half2_rn(fmaxf(f2.x + bb.x, 0.f), fmaxf(f2.y + bb.y, 0.f));
        __half2 o3 = __floats2half2_rn(fmaxf(f3.x + bb.z, 0.f), fmaxf(f3.y + bb.w, 0.f));
        float4 packed;
        __half2* pp = (__half2*)&packed;
        pp[0] = o0; pp[1] = o1; pp[2] = o2; pp[3] = o3;
        ((float4*)outx)[(size_t)node * 16 + l] = packed;
    }
}

// ---------------- fused pool + head: one block (128 threads) per graph ----------------
__device__ __forceinline__ int lower_bound_i(const int* __restrict__ a, int n, int val) {
    int lo = 0, hi = n;
    while (lo < hi) {
        int mid = (lo + hi) >> 1;
        if (a[mid] < val) lo = mid + 1; else hi = mid;
    }
    return lo;
}

__global__ void pool_head_kernel(const __half* __restrict__ x,
                                 const int* __restrict__ batch,
                                 const float* __restrict__ Wfc,
                                 const float* __restrict__ bfc,
                                 const float* __restrict__ Wout,
                                 const float* __restrict__ bout,
                                 float* __restrict__ out, int N) {
    int gr = blockIdx.x;
    int t = threadIdx.x;  // 0..127
    int j2 = t & 63, w = t >> 6;
    __shared__ float2 spart[2][64];
    __shared__ float sg[128];
    __shared__ float sred[128];
    int beg = lower_bound_i(batch, N, gr);
    int end = lower_bound_i(batch, N, gr + 1);
    const __half2* x2 = (const __half2*)x;  // row stride 64 half2
    float2 acc = make_float2(0.f, 0.f);
    for (int i = beg + w; i < end; i += 2) {
        float2 a = __half22float2(x2[(size_t)i * 64 + j2]);
        acc.x += a.x; acc.y += a.y;
    }
    spart[w][j2] = acc;
    __syncthreads();
    if (t < 64) {
        float inv = 1.0f / fmaxf((float)(end - beg), 1.0f);
        float2 s0 = spart[0][t], s1 = spart[1][t];
        sg[2 * t] = (s0.x + s1.x) * inv;
        sg[2 * t + 1] = (s0.y + s1.y) * inv;
    }
    __syncthreads();
    int j = t;
    float a = bfc[j];
#pragma unroll
    for (int k = 0; k < 128; k++) a += sg[k] * Wfc[k * 128 + j];
    float f = fmaxf(a, 0.f);
    sred[j] = f * Wout[j];
    __syncthreads();
    if (j < 64) sred[j] += sred[j + 64];
    __syncthreads();
    if (j < 64) {
        float v = sred[j];
#pragma unroll
        for (int off = 32; off > 0; off >>= 1) v += __shfl_down(v, off);
        if (j == 0) {
            float logit = v + bout[0];
            out[gr] = 1.0f / (1.0f + expf(-logit));
            out[NUM_GRAPHS + gr] = logit;
        }
    }
}

extern "C" void kernel_launch(void* const* d_in, const int* in_sizes, int n_in,
                              void* d_out, int out_size, void* d_ws, size_t ws_size,
                              hipStream_t stream) {
    const int* tok   = (const int*)d_in[0];
    const int* eidx  = (const int*)d_in[1];
    const int* batch = (const int*)d_in[2];
    const float* emb = (const float*)d_in[3];
    const float* Wp  = (const float*)d_in[4];
    const float* bp  = (const float*)d_in[5];
    const float* W1  = (const float*)d_in[6];
    const float* b1  = (const float*)d_in[7];
    const float* W2  = (const float*)d_in[8];
    const float* b2  = (const float*)d_in[9];
    const float* Wfc = (const float*)d_in[10];
    const float* bfc = (const float*)d_in[11];
    const float* Wout= (const float*)d_in[12];
    const float* bout= (const float*)d_in[13];
    float* out = (float*)d_out;

    const int N = in_sizes[2];
    const int E = in_sizes[1] / 2;
    const int* src = eidx;
    const int* dst = eidx + E;
    const int Np = (N + 3) & ~3;
    const int nbuck = (N + 255) / 256;               // 391 for N=100k
    const int nchunk = (E + CHUNK - 1) / CHUNK;      // 196
    const int emb_n4 = in_sizes[3] / 4;              // float4 count of emb

    // workspace layout (float units)
    float* ws = (float*)d_ws;
    size_t off = 0;
    float* dis     = ws + off;            off += Np;
    __half* mean16 = (__half*)(ws + off); off += (size_t)Np * 32;
    __half* agg16  = (__half*)(ws + off); off += (size_t)Np * 32;
    float* rowsum  = ws + off;            off += Np;
    __half* h2buf  = (__half*)(ws + off); off += (size_t)Np * 64;
    __half* xfin16 = (__half*)(ws + off); off += (size_t)Np * 64;
    __half* emb16  = (__half*)(ws + off); off += (size_t)(in_sizes[3] / 2 + 4);
    _Float16* Wf16t = (_Float16*)(ws + off); off += 4096;
    _Float16* W2t   = (_Float16*)(ws + off); off += 8192;
    float* bf      = ws + off;            off += 128;
    int* row_start = (int*)(ws + off);    off += Np + 4;
    int* staged    = (int*)(ws + off);    off += E;
    int* bucket_cnt    = (int*)(ws + off); off += NBUCK_MAX;
    int* bucket_base   = (int*)(ws + off); off += NBUCK_MAX + 8;
    int* bucket_cursor = (int*)(ws + off); off += NBUCK_MAX;
    int2* csr      = (int2*)(ws + off);   // E int2

    // --- fused weight prep + emb fp16 conversion ---
    prep_weights_kernel<<<128, 128, 0, stream>>>(Wp, W1, W2, bp, Wf16t, W2t, bf);
    convert_emb_kernel<<<(emb_n4 + 255) / 256, 256, 0, stream>>>(emb, emb16, emb_n4);

    // --- bucketed counting sort -> row_start, dis, csr(+rowsum) ---
    hipMemsetAsync(bucket_cnt, 0, nbuck * sizeof(int), stream);
    bucket_hist_kernel<<<nchunk, 512, 0, stream>>>(dst, bucket_cnt, E, nbuck);
    bucket_scan_kernel<<<1, 512, 0, stream>>>(bucket_cnt, bucket_base, bucket_cursor, nbuck);
    binscatter_kernel<<<nchunk, 512, 0, stream>>>(src, dst, bucket_base, bucket_cursor,
                                                  staged, E, nbuck);
    bucket_count_kernel<<<nbuck, 256, 0, stream>>>(staged, bucket_base, row_start, dis, N, E);
    csr_write_kernel<<<nbuck, 256, 0, stream>>>(staged, bucket_base, row_start, dis,
                                                csr, rowsum, N);

    // --- embed + token-mean (fp16 table) -> mean16 ---
    embed_mean_kernel<<<(N + 3) / 4, 256, 0, stream>>>(tok, emb16, mean16, N);

    // --- 64-dim aggregate (fp16 packed) -> agg16 ---
    agg64_kernel<<<(N + 3) / 4, 256, 0, stream>>>(mean16, row_start, csr, dis, agg16, N);

    // --- MFMA dense chain: h2 = relu(agg@Wf + rowsum*bf + b1) @ W2 -> fp16 ---
    dense_chain_mfma_kernel<<<(N + NB - 1) / NB, 256, 0, stream>>>(agg16, rowsum, Wf16t,
                                                                   bf, b1, W2t, h2buf, N);

    // --- layer 2 aggregate (fp16 packed) + b2 + ReLU -> xfin16 ---
    gcn_agg128_kernel<<<(N + 3) / 4, 256, 0, stream>>>(h2buf, row_start, csr, dis, b2,
                                                       xfin16, N);

    // --- fused global mean pool + head ---
    pool_head_kernel<<<NUM_GRAPHS, 128, 0, stream>>>(xfin16, batch, Wfc, bfc, Wout, bout,
                                                     out, N);
}